// Round 5
// baseline (184.183 us; speedup 1.0000x reference)
//
#include <hip/hip_runtime.h>
#include <hip/hip_bf16.h>

#define BB 8
#define NN 2048
#define DD 256

typedef _Float16 half8 __attribute__((ext_vector_type(8)));
typedef _Float16 half4 __attribute__((ext_vector_type(4)));
typedef float f32x4 __attribute__((ext_vector_type(4)));

__device__ __forceinline__ half8 cvt8(const float* __restrict__ p) {
    f32x4 a = *(const f32x4*)p;
    f32x4 b = *(const f32x4*)(p + 4);
    half8 h;
    h[0] = (_Float16)a[0]; h[1] = (_Float16)a[1];
    h[2] = (_Float16)a[2]; h[3] = (_Float16)a[3];
    h[4] = (_Float16)b[0]; h[5] = (_Float16)b[1];
    h[6] = (_Float16)b[2]; h[7] = (_Float16)b[3];
    return h;
}

// ---------------- Kernel A: qh = (x@Wq^T)*scale, kh = x@Wk^T (fp16 out) -------
// 1024 blocks: rowblk = bid>>2 (64 token rows), tq = bid&3 (4 col-tiles each).
// W tiles: flat [16][256] fp16, elem ^= (row&7)<<3 XOR swizzle (conflict-free
// staging writes and fragment reads, verified bank-uniform).
__global__ void __launch_bounds__(256)
qk_proj(const float* __restrict__ x, const float* __restrict__ Wq,
        const float* __restrict__ Wk, _Float16* __restrict__ qh,
        _Float16* __restrict__ kh) {
    __shared__ __align__(16) _Float16 Wql[16 * 256];
    __shared__ __align__(16) _Float16 Wkl[16 * 256];
    const int tid = threadIdx.x;
    const int wave = tid >> 6, lane = tid & 63;
    const int g = lane >> 4, l16 = lane & 15;
    const int rowblk = blockIdx.x >> 2, tq = blockIdx.x & 3;
    const size_t r0 = ((size_t)rowblk * 4 + wave) * 16;

    half8 xa[8];
#pragma unroll
    for (int c = 0; c < 8; ++c)
        xa[c] = cvt8(x + (r0 + l16) * DD + c * 32 + g * 8);

    const int sel = tid >> 7;
    const int tt  = tid & 127;
    const int wrow = tt >> 3;

    for (int i = 0; i < 4; ++i) {
        const int t = tq * 4 + i;
        __syncthreads();
        {
            const float* src = (sel ? Wk : Wq) + (size_t)(t * 16 + wrow) * DD;
            _Float16* dst = sel ? Wkl : Wql;
#pragma unroll
            for (int j = 0; j < 4; ++j) {
                int chunk = (tt & 7) * 4 + j;            // 16B quad index 0..31
                int e = chunk * 8;
                dst[wrow * 256 + (e ^ ((wrow & 7) << 3))] =
                    ((half8*)0, 0), *(half8*)&dst[wrow * 256 + (e ^ ((wrow & 7) << 3))] = cvt8(src + e);
            }
        }
        __syncthreads();
        f32x4 aq = {0.f, 0.f, 0.f, 0.f}, ak = {0.f, 0.f, 0.f, 0.f};
#pragma unroll
        for (int c = 0; c < 8; ++c) {
            int u = (c * 32 + g * 8) ^ ((l16 & 7) << 3);
            half8 bq = *(const half8*)&Wql[l16 * 256 + u];
            half8 bk = *(const half8*)&Wkl[l16 * 256 + u];
            aq = __builtin_amdgcn_mfma_f32_16x16x32_f16(xa[c], bq, aq, 0, 0, 0);
            ak = __builtin_amdgcn_mfma_f32_16x16x32_f16(xa[c], bk, ak, 0, 0, 0);
        }
#pragma unroll
        for (int r = 0; r < 4; ++r) {
            size_t row = r0 + g * 4 + r;
            qh[row * DD + t * 16 + l16] = (_Float16)(aq[r] * 0.0625f);
            kh[row * DD + t * 16 + l16] = (_Float16)ak[r];
        }
    }
}

// ---------------- Kernel B: xT[b][d][n] = (fp16) x[b][n][d] ----------------
__global__ void __launch_bounds__(256)
x_transpose(const float* __restrict__ x, _Float16* __restrict__ xT) {
    __shared__ _Float16 tl[32][33];
    const int b = blockIdx.z;
    const int n0 = blockIdx.y * 32, d0 = blockIdx.x * 32;
    const int c = threadIdx.x & 31, rq = threadIdx.x >> 5;
#pragma unroll
    for (int i = 0; i < 4; ++i) {
        int row = rq + i * 8;
        tl[row][c] = (_Float16)x[((size_t)b * NN + n0 + row) * DD + d0 + c];
    }
    __syncthreads();
#pragma unroll
    for (int i = 0; i < 4; ++i) {
        int dr = rq + i * 8;
        xT[((size_t)b * DD + d0 + dr) * NN + n0 + c] = tl[c][dr];
    }
}

// ---------------- Kernel C: flash attention ----------------
// VGPR-staged LDS tiles (L2-friendly linear global reads), swizzled LDS writes.
// Kl: flat [32][256] fp16, elem ^= (row&7)<<3. Vl: flat [256][32] unpadded
// (naturally conflict-free). Pl: per-wave P relayout. LDS 37.9KB -> 4 blk/CU.
// Grid BB*(NN/64)*S, bid&7 = batch -> XCD L2 affinity. Op stored permuted
// for 128B-coalesced fp16 partial writes.
__global__ void __launch_bounds__(256, 4)
attn(const _Float16* __restrict__ qh, const _Float16* __restrict__ kh,
     const _Float16* __restrict__ xT, float* __restrict__ out,
     _Float16* __restrict__ Op, float* __restrict__ ml, int lgS) {
    __shared__ __align__(16) _Float16 Kl[32 * 256];
    __shared__ __align__(16) _Float16 Vl[256 * 32];
    __shared__ __align__(16) _Float16 Pl[4][16][40];
    const int tid = threadIdx.x;
    const int wave = tid >> 6, lane = tid & 63;
    const int g = lane >> 4, l16 = lane & 15;
    const int S = 1 << lgS;
    const int b = blockIdx.x & 7;
    const int tt = blockIdx.x >> 3;
    const int s = tt & (S - 1);
    const int qb = tt >> lgS;
    const int q0 = qb * 64 + wave * 16;
    const int kvlen = NN >> lgS;
    const int kv_begin = s * kvlen;

    const _Float16* qp = qh + ((size_t)b * NN + q0) * DD;
    const _Float16* kb = kh + (size_t)b * NN * DD;
    const _Float16* vb = xT + (size_t)b * DD * NN;

    // staging indices
    const int kr = tid >> 3;          // K tile row 0..31 (8 lanes/row)
    const int kq = tid & 7;
    const int vdb = tid >> 2;         // V d-row base (+ p*64), 4 lanes/row
    const int vch = (tid & 3) * 8;

    half8 qf[8];
#pragma unroll
    for (int c = 0; c < 8; ++c)
        qf[c] = *(const half8*)(qp + (size_t)l16 * DD + c * 32 + g * 8);

    f32x4 O[16];
    f32x4 zero = {0.f, 0.f, 0.f, 0.f};
#pragma unroll
    for (int t = 0; t < 16; ++t) O[t] = zero;
    float m[4] = {-1e30f, -1e30f, -1e30f, -1e30f};
    float l[4] = {0.f, 0.f, 0.f, 0.f};

    for (int kv0 = kv_begin; kv0 < kv_begin + kvlen; kv0 += 32) {
        {   // stage K: linear global read, XOR-swizzled ds_write
            const _Float16* ksrc = kb + (size_t)(kv0 + kr) * DD;
            const int kswz = (kr & 7) << 3;
#pragma unroll
            for (int j = 0; j < 4; ++j) {
                int e = (kq + 8 * j) * 8;
                *(half8*)&Kl[kr * 256 + (e ^ kswz)] = *(const half8*)(ksrc + e);
            }
        }
        {   // stage V: linear both sides
#pragma unroll
            for (int p = 0; p < 4; ++p) {
                int d = p * 64 + vdb;
                *(half8*)&Vl[d * 32 + vch] = *(const half8*)(vb + (size_t)d * NN + kv0 + vch);
            }
        }
        __syncthreads();

        // QK^T
        f32x4 s0 = zero, s1 = zero;
#pragma unroll
        for (int c = 0; c < 8; ++c) {
            int u = (c * 32 + g * 8) ^ ((l16 & 7) << 3);
            half8 k0 = *(const half8*)&Kl[l16 * 256 + u];
            half8 k1 = *(const half8*)&Kl[(16 + l16) * 256 + u];
            s0 = __builtin_amdgcn_mfma_f32_16x16x32_f16(qf[c], k0, s0, 0, 0, 0);
            s1 = __builtin_amdgcn_mfma_f32_16x16x32_f16(qf[c], k1, s1, 0, 0, 0);
        }

        float p0[4], p1[4], tm[4];
#pragma unroll
        for (int r = 0; r < 4; ++r) {
            p0[r] = s0[r];
            p1[r] = s1[r];
            tm[r] = fmaxf(p0[r], p1[r]);
        }
#pragma unroll
        for (int mask = 1; mask < 16; mask <<= 1) {
#pragma unroll
            for (int r = 0; r < 4; ++r)
                tm[r] = fmaxf(tm[r], __shfl_xor(tm[r], mask));
        }
        bool need = false;
#pragma unroll
        for (int r = 0; r < 4; ++r) need = need || (tm[r] > m[r] + 8.f);
        if (__ballot(need)) {
#pragma unroll
            for (int r = 0; r < 4; ++r) {
                float nm = fmaxf(m[r], tm[r]);
                float al = __expf(m[r] - nm);
                m[r] = nm;
                l[r] *= al;
#pragma unroll
                for (int t = 0; t < 16; ++t) O[t][r] *= al;
            }
        }
        float rs[4];
#pragma unroll
        for (int r = 0; r < 4; ++r) {
            p0[r] = __expf(p0[r] - m[r]);
            p1[r] = __expf(p1[r] - m[r]);
            rs[r] = p0[r] + p1[r];
        }
#pragma unroll
        for (int mask = 1; mask < 16; mask <<= 1) {
#pragma unroll
            for (int r = 0; r < 4; ++r) rs[r] += __shfl_xor(rs[r], mask);
        }
#pragma unroll
        for (int r = 0; r < 4; ++r) l[r] += rs[r];

        // P relayout through wave-private LDS
#pragma unroll
        for (int r = 0; r < 4; ++r) {
            Pl[wave][g * 4 + r][l16]      = (_Float16)p0[r];
            Pl[wave][g * 4 + r][16 + l16] = (_Float16)p1[r];
        }
        asm volatile("s_waitcnt lgkmcnt(0)" ::: "memory");
        half8 pf = *(const half8*)&Pl[wave][l16][g * 8];

        // PV
#pragma unroll
        for (int t = 0; t < 16; ++t) {
            half8 vf = *(const half8*)&Vl[(t * 16 + l16) * 32 + g * 8];
            O[t] = __builtin_amdgcn_mfma_f32_16x16x32_f16(pf, vf, O[t], 0, 0, 0);
        }
        __syncthreads();
    }

    if (lgS == 0) {
        float rl[4];
#pragma unroll
        for (int r = 0; r < 4; ++r) rl[r] = 1.0f / l[r];
        float* ob = out + ((size_t)b * NN + q0) * DD;
#pragma unroll
        for (int t = 0; t < 16; ++t) {
#pragma unroll
            for (int r = 0; r < 4; ++r)
                ob[(size_t)(g * 4 + r) * DD + t * 16 + l16] = O[t][r] * rl[r];
        }
    } else {
        // permuted per-wave layout: 128B-coalesced fp16 stores
        float rl[4];
#pragma unroll
        for (int r = 0; r < 4; ++r) rl[r] = 1.0f / l[r];
        _Float16* ow = Op + (((size_t)s * BB + b) * NN + q0) * DD;
#pragma unroll
        for (int t = 0; t < 16; ++t) {
#pragma unroll
            for (int r = 0; r < 4; ++r)
                ow[(t * 4 + r) * 64 + lane] = (_Float16)(O[t][r] * rl[r]);
        }
        if (l16 == 0) {
            float* mlp = ml + (((size_t)s * BB + b) * NN + q0) * 2;
#pragma unroll
            for (int r = 0; r < 4; ++r) {
                mlp[(g * 4 + r) * 2]     = m[r];
                mlp[(g * 4 + r) * 2 + 1] = l[r];
            }
        }
    }
}

// ---------------- Kernel D: combine permuted fp16 partials ----------------
__global__ void __launch_bounds__(256)
combine(const _Float16* __restrict__ Op, const float* __restrict__ ml,
        float* __restrict__ out, int S) {
    const int row = blockIdx.x * 4 + (threadIdx.x >> 6);  // flat row in [0, BB*NN)
    const int c0  = (threadIdx.x & 63) * 4;               // col 0..252
    // inverse of the permuted wave layout
    const int widx = ((c0 >> 4) * 4 + (row & 3)) * 64 + ((row >> 2) & 3) * 16 + (c0 & 15);
    const size_t rbase = (size_t)(row & ~15) * DD + widx;

    float M = -1e30f;
    for (int s = 0; s < S; ++s)
        M = fmaxf(M, ml[((size_t)s * BB * NN + row) * 2]);
    float wsum = 0.f;
    f32x4 acc = {0.f, 0.f, 0.f, 0.f};
    for (int s = 0; s < S; ++s) {
        const float* mlp = ml + ((size_t)s * BB * NN + row) * 2;
        float w = __expf(mlp[0] - M) * mlp[1];
        wsum += w;
        half4 o = *(const half4*)(Op + (size_t)s * BB * NN * DD + rbase);
        acc[0] += w * (float)o[0]; acc[1] += w * (float)o[1];
        acc[2] += w * (float)o[2]; acc[3] += w * (float)o[3];
    }
    float inv = 1.0f / wsum;
    f32x4 res = {acc[0] * inv, acc[1] * inv, acc[2] * inv, acc[3] * inv};
    *(f32x4*)(out + (size_t)row * DD + c0) = res;
}

extern "C" void kernel_launch(void* const* d_in, const int* in_sizes, int n_in,
                              void* d_out, int out_size, void* d_ws, size_t ws_size,
                              hipStream_t stream) {
    const float* x  = (const float*)d_in[0];
    const float* Wq = (const float*)d_in[1];
    const float* Wk = (const float*)d_in[2];
    float* out = (float*)d_out;

    const size_t NTOK = (size_t)BB * NN;
    const size_t HBUF = NTOK * DD * sizeof(_Float16);
    _Float16* qh = (_Float16*)d_ws;
    _Float16* kh = qh + NTOK * DD;
    _Float16* xT = kh + NTOK * DD;
    const size_t base = 3 * HBUF;
    const size_t OSZ  = NTOK * DD * sizeof(_Float16);
    const size_t MLSZ = NTOK * 2 * sizeof(float);

    int lgS = 0;
    if (ws_size >= base + 4 * (OSZ + MLSZ)) lgS = 2;
    else if (ws_size >= base + 2 * (OSZ + MLSZ)) lgS = 1;
    const int S = 1 << lgS;

    _Float16* Op = (_Float16*)((char*)d_ws + base);
    float* ml = (float*)((char*)d_ws + base + (size_t)S * OSZ);

    qk_proj<<<dim3(BB * NN / 64 * 4), dim3(256), 0, stream>>>(x, Wq, Wk, qh, kh);
    x_transpose<<<dim3(DD / 32, NN / 32, BB), dim3(256), 0, stream>>>(x, xT);
    attn<<<dim3(BB * (NN / 64) * S), dim3(256), 0, stream>>>(qh, kh, xT, out, Op, ml, lgS);
    if (S > 1)
        combine<<<dim3(BB * NN / 4), dim3(256), 0, stream>>>(Op, ml, out, S);
}

// Round 7
// 142.855 us; speedup vs baseline: 1.2893x; 1.2893x over previous
//
#include <hip/hip_runtime.h>
#include <hip/hip_bf16.h>

#define BB 8
#define NN 2048
#define DD 256

typedef _Float16 half8 __attribute__((ext_vector_type(8)));
typedef _Float16 half4 __attribute__((ext_vector_type(4)));
typedef float f32x4 __attribute__((ext_vector_type(4)));

__device__ __forceinline__ half8 cvt8(const float* __restrict__ p) {
    f32x4 a = *(const f32x4*)p;
    f32x4 b = *(const f32x4*)(p + 4);
    half8 h;
    h[0] = (_Float16)a[0]; h[1] = (_Float16)a[1];
    h[2] = (_Float16)a[2]; h[3] = (_Float16)a[3];
    h[4] = (_Float16)b[0]; h[5] = (_Float16)b[1];
    h[6] = (_Float16)b[2]; h[7] = (_Float16)b[3];
    return h;
}

// ---------------- Kernel A: qh = (x@Wq^T)*scale, kh = x@Wk^T (fp16 out) -------
// R2's proven version: 512 blocks, 4 waves x 16 token-rows, 8 col-tiles each.
__global__ void __launch_bounds__(256)
qk_proj(const float* __restrict__ x, const float* __restrict__ Wq,
        const float* __restrict__ Wk, _Float16* __restrict__ qh,
        _Float16* __restrict__ kh) {
    __shared__ __align__(16) _Float16 Wql[16][264];
    __shared__ __align__(16) _Float16 Wkl[16][264];
    const int tid = threadIdx.x;
    const int wave = tid >> 6, lane = tid & 63;
    const int g = lane >> 4, l16 = lane & 15;
    const int rowblk = blockIdx.x >> 1, thalf = blockIdx.x & 1;
    const size_t r0 = ((size_t)rowblk * 4 + wave) * 16;

    half8 xa[8];
#pragma unroll
    for (int c = 0; c < 8; ++c)
        xa[c] = cvt8(x + (r0 + l16) * DD + c * 32 + g * 8);

    for (int i = 0; i < 8; ++i) {
        const int t = thalf * 8 + i;
        __syncthreads();
        {
            const int sel = tid >> 7;
            const int tt  = tid & 127;
            const int row = tt >> 3;
            const int col = (tt & 7) * 32;
            const float* src = (sel ? Wk : Wq) + (size_t)(t * 16 + row) * DD + col;
            _Float16* dst = sel ? &Wkl[row][col] : &Wql[row][col];
#pragma unroll
            for (int j = 0; j < 4; ++j)
                *(half8*)(dst + j * 8) = cvt8(src + j * 8);
        }
        __syncthreads();
        f32x4 aq = {0.f, 0.f, 0.f, 0.f}, ak = {0.f, 0.f, 0.f, 0.f};
#pragma unroll
        for (int c = 0; c < 8; ++c) {
            half8 bq = *(const half8*)&Wql[l16][c * 32 + g * 8];
            half8 bk = *(const half8*)&Wkl[l16][c * 32 + g * 8];
            aq = __builtin_amdgcn_mfma_f32_16x16x32_f16(xa[c], bq, aq, 0, 0, 0);
            ak = __builtin_amdgcn_mfma_f32_16x16x32_f16(xa[c], bk, ak, 0, 0, 0);
        }
#pragma unroll
        for (int r = 0; r < 4; ++r) {
            size_t row = r0 + g * 4 + r;
            qh[row * DD + t * 16 + l16] = (_Float16)(aq[r] * 0.0625f);
            kh[row * DD + t * 16 + l16] = (_Float16)ak[r];
        }
    }
}

// ---------------- Kernel B: xT[b][d][n] = (fp16) x[b][n][d] ----------------
__global__ void __launch_bounds__(256)
x_transpose(const float* __restrict__ x, _Float16* __restrict__ xT) {
    __shared__ _Float16 tl[32][33];
    const int b = blockIdx.z;
    const int n0 = blockIdx.y * 32, d0 = blockIdx.x * 32;
    const int c = threadIdx.x & 31, rq = threadIdx.x >> 5;
#pragma unroll
    for (int i = 0; i < 4; ++i) {
        int row = rq + i * 8;
        tl[row][c] = (_Float16)x[((size_t)b * NN + n0 + row) * DD + d0 + c];
    }
    __syncthreads();
#pragma unroll
    for (int i = 0; i < 4; ++i) {
        int dr = rq + i * 8;
        xT[((size_t)b * DD + d0 + dr) * NN + n0 + c] = tl[c][dr];
    }
}

// ---------------- Kernel C: flash attention ----------------
// R2 structure (VGPR staging, padded Kl, Pl relayout), with:
//  - NO min-waves launch bound (R3/R4/R5 all spilled: 64 VGPRs < O[16] alone)
//  - Vl flat [256][32] UNPADDED, LINEAR both sides (bank-verified: write and
//    PV-read both hit the structural wave64-b128 minimum; R6's XOR was
//    non-injective across 8-row boundaries -> correctness bug)
//  - LDS 38400B -> 4 blocks/CU at full VGPRs
//  - coalesced permuted fp16 Op partial stores
__global__ void __launch_bounds__(256)
attn(const _Float16* __restrict__ qh, const _Float16* __restrict__ kh,
     const _Float16* __restrict__ xT, float* __restrict__ out,
     _Float16* __restrict__ Op, float* __restrict__ ml, int lgS) {
    __shared__ __align__(16) _Float16 Kl[32][264];
    __shared__ __align__(16) _Float16 Vl[256 * 32];
    __shared__ __align__(16) _Float16 Pl[4][16][40];
    const int tid = threadIdx.x;
    const int wave = tid >> 6, lane = tid & 63;
    const int g = lane >> 4, l16 = lane & 15;
    const int S = 1 << lgS;
    const int b = blockIdx.x & 7;
    const int tt = blockIdx.x >> 3;
    const int s = tt & (S - 1);
    const int qb = tt >> lgS;
    const int q0 = qb * 64 + wave * 16;
    const int kvlen = NN >> lgS;
    const int kv_begin = s * kvlen;

    const _Float16* qp = qh + ((size_t)b * NN + q0) * DD;
    const _Float16* kb = kh + (size_t)b * NN * DD;
    const _Float16* vb = xT + (size_t)b * DD * NN;

    half8 qf[8];
#pragma unroll
    for (int c = 0; c < 8; ++c)
        qf[c] = *(const half8*)(qp + (size_t)l16 * DD + c * 32 + g * 8);

    f32x4 O[16];
    f32x4 zero = {0.f, 0.f, 0.f, 0.f};
#pragma unroll
    for (int t = 0; t < 16; ++t) O[t] = zero;
    float m[4] = {-1e30f, -1e30f, -1e30f, -1e30f};
    float l[4] = {0.f, 0.f, 0.f, 0.f};

    for (int kv0 = kv_begin; kv0 < kv_begin + kvlen; kv0 += 32) {
        __syncthreads();
        {   // stage K tile: 32 rows x 256 d (R2 pattern, conflict-free)
            const int r = tid >> 3;
            const int ch = (tid & 7) * 8;
            const _Float16* src = kb + (size_t)(kv0 + r) * DD + ch;
#pragma unroll
            for (int j = 0; j < 4; ++j)
                *(half8*)&Kl[r][ch + j * 64] = *(const half8*)(src + j * 64);
        }
        {   // stage V tile: linear global read, linear LDS write
            const int vch = (tid & 3) * 8;
#pragma unroll
            for (int p = 0; p < 4; ++p) {
                int d = p * 64 + (tid >> 2);
                *(half8*)&Vl[d * 32 + vch] =
                    *(const half8*)(vb + (size_t)d * NN + kv0 + vch);
            }
        }
        __syncthreads();

        // QK^T
        f32x4 s0 = zero, s1 = zero;
#pragma unroll
        for (int c = 0; c < 8; ++c) {
            half8 k0 = *(const half8*)&Kl[l16][c * 32 + g * 8];
            half8 k1 = *(const half8*)&Kl[16 + l16][c * 32 + g * 8];
            s0 = __builtin_amdgcn_mfma_f32_16x16x32_f16(qf[c], k0, s0, 0, 0, 0);
            s1 = __builtin_amdgcn_mfma_f32_16x16x32_f16(qf[c], k1, s1, 0, 0, 0);
        }

        float p0[4], p1[4], tm[4];
#pragma unroll
        for (int r = 0; r < 4; ++r) {
            p0[r] = s0[r];
            p1[r] = s1[r];
            tm[r] = fmaxf(p0[r], p1[r]);
        }
#pragma unroll
        for (int mask = 1; mask < 16; mask <<= 1) {
#pragma unroll
            for (int r = 0; r < 4; ++r)
                tm[r] = fmaxf(tm[r], __shfl_xor(tm[r], mask));
        }
        bool need = false;
#pragma unroll
        for (int r = 0; r < 4; ++r) need = need || (tm[r] > m[r] + 8.f);
        if (__ballot(need)) {
#pragma unroll
            for (int r = 0; r < 4; ++r) {
                float nm = fmaxf(m[r], tm[r]);
                float al = __expf(m[r] - nm);
                m[r] = nm;
                l[r] *= al;
#pragma unroll
                for (int t = 0; t < 16; ++t) O[t][r] *= al;
            }
        }
        float rs[4];
#pragma unroll
        for (int r = 0; r < 4; ++r) {
            p0[r] = __expf(p0[r] - m[r]);
            p1[r] = __expf(p1[r] - m[r]);
            rs[r] = p0[r] + p1[r];
        }
#pragma unroll
        for (int mask = 1; mask < 16; mask <<= 1) {
#pragma unroll
            for (int r = 0; r < 4; ++r) rs[r] += __shfl_xor(rs[r], mask);
        }
#pragma unroll
        for (int r = 0; r < 4; ++r) l[r] += rs[r];

        // P relayout through wave-private LDS
#pragma unroll
        for (int r = 0; r < 4; ++r) {
            Pl[wave][g * 4 + r][l16]      = (_Float16)p0[r];
            Pl[wave][g * 4 + r][16 + l16] = (_Float16)p1[r];
        }
        asm volatile("s_waitcnt lgkmcnt(0)" ::: "memory");
        half8 pf = *(const half8*)&Pl[wave][l16][g * 8];

        // PV (linear V reads, structurally conflict-free)
#pragma unroll
        for (int t = 0; t < 16; ++t) {
            half8 vf = *(const half8*)&Vl[(t * 16 + l16) * 32 + g * 8];
            O[t] = __builtin_amdgcn_mfma_f32_16x16x32_f16(pf, vf, O[t], 0, 0, 0);
        }
    }

    if (lgS == 0) {
        float rl[4];
#pragma unroll
        for (int r = 0; r < 4; ++r) rl[r] = 1.0f / l[r];
        float* ob = out + ((size_t)b * NN + q0) * DD;
#pragma unroll
        for (int t = 0; t < 16; ++t) {
#pragma unroll
            for (int r = 0; r < 4; ++r)
                ob[(size_t)(g * 4 + r) * DD + t * 16 + l16] = O[t][r] * rl[r];
        }
    } else {
        // permuted per-wave layout: 128B-coalesced fp16 stores
        float rl[4];
#pragma unroll
        for (int r = 0; r < 4; ++r) rl[r] = 1.0f / l[r];
        _Float16* ow = Op + (((size_t)s * BB + b) * NN + q0) * DD;
#pragma unroll
        for (int t = 0; t < 16; ++t) {
#pragma unroll
            for (int r = 0; r < 4; ++r)
                ow[(t * 4 + r) * 64 + lane] = (_Float16)(O[t][r] * rl[r]);
        }
        if (l16 == 0) {
            float* mlp = ml + (((size_t)s * BB + b) * NN + q0) * 2;
#pragma unroll
            for (int r = 0; r < 4; ++r) {
                mlp[(g * 4 + r) * 2]     = m[r];
                mlp[(g * 4 + r) * 2 + 1] = l[r];
            }
        }
    }
}

// ---------------- Kernel D: combine permuted fp16 partials ----------------
__global__ void __launch_bounds__(256)
combine(const _Float16* __restrict__ Op, const float* __restrict__ ml,
        float* __restrict__ out, int S) {
    const int row = blockIdx.x * 4 + (threadIdx.x >> 6);  // flat row in [0, BB*NN)
    const int c0  = (threadIdx.x & 63) * 4;               // col 0..252
    // inverse of the permuted wave layout
    const int widx = ((c0 >> 4) * 4 + (row & 3)) * 64 + ((row >> 2) & 3) * 16 + (c0 & 15);
    const size_t rbase = (size_t)(row & ~15) * DD + widx;

    float M = -1e30f;
    for (int s = 0; s < S; ++s)
        M = fmaxf(M, ml[((size_t)s * BB * NN + row) * 2]);
    float wsum = 0.f;
    f32x4 acc = {0.f, 0.f, 0.f, 0.f};
    for (int s = 0; s < S; ++s) {
        const float* mlp = ml + ((size_t)s * BB * NN + row) * 2;
        float w = __expf(mlp[0] - M) * mlp[1];
        wsum += w;
        half4 o = *(const half4*)(Op + (size_t)s * BB * NN * DD + rbase);
        acc[0] += w * (float)o[0]; acc[1] += w * (float)o[1];
        acc[2] += w * (float)o[2]; acc[3] += w * (float)o[3];
    }
    float inv = 1.0f / wsum;
    f32x4 res = {acc[0] * inv, acc[1] * inv, acc[2] * inv, acc[3] * inv};
    *(f32x4*)(out + (size_t)row * DD + c0) = res;
}

extern "C" void kernel_launch(void* const* d_in, const int* in_sizes, int n_in,
                              void* d_out, int out_size, void* d_ws, size_t ws_size,
                              hipStream_t stream) {
    const float* x  = (const float*)d_in[0];
    const float* Wq = (const float*)d_in[1];
    const float* Wk = (const float*)d_in[2];
    float* out = (float*)d_out;

    const size_t NTOK = (size_t)BB * NN;
    const size_t HBUF = NTOK * DD * sizeof(_Float16);
    _Float16* qh = (_Float16*)d_ws;
    _Float16* kh = qh + NTOK * DD;
    _Float16* xT = kh + NTOK * DD;
    const size_t base = 3 * HBUF;
    const size_t OSZ  = NTOK * DD * sizeof(_Float16);
    const size_t MLSZ = NTOK * 2 * sizeof(float);

    int lgS = 0;
    if (ws_size >= base + 4 * (OSZ + MLSZ)) lgS = 2;
    else if (ws_size >= base + 2 * (OSZ + MLSZ)) lgS = 1;
    const int S = 1 << lgS;

    _Float16* Op = (_Float16*)((char*)d_ws + base);
    float* ml = (float*)((char*)d_ws + base + (size_t)S * OSZ);

    qk_proj<<<dim3(BB * NN / 64 * 2), dim3(256), 0, stream>>>(x, Wq, Wk, qh, kh);
    x_transpose<<<dim3(DD / 32, NN / 32, BB), dim3(256), 0, stream>>>(x, xT);
    attn<<<dim3(BB * (NN / 64) * S), dim3(256), 0, stream>>>(qh, kh, xT, out, Op, ml, lgS);
    if (S > 1)
        combine<<<dim3(BB * NN / 4), dim3(256), 0, stream>>>(Op, ml, out, S);
}

// Round 8
// 128.059 us; speedup vs baseline: 1.4383x; 1.1155x over previous
//
#include <hip/hip_runtime.h>
#include <hip/hip_bf16.h>

#define BB 8
#define NN 2048
#define DD 256

typedef _Float16 half8 __attribute__((ext_vector_type(8)));
typedef _Float16 half4 __attribute__((ext_vector_type(4)));
typedef _Float16 half2v __attribute__((ext_vector_type(2)));
typedef float f32x4 __attribute__((ext_vector_type(4)));
typedef unsigned int uint4v __attribute__((ext_vector_type(4)));

__device__ __forceinline__ half8 cvt8(const float* __restrict__ p) {
    f32x4 a = *(const f32x4*)p;
    f32x4 b = *(const f32x4*)(p + 4);
    half8 h;
    h[0] = (_Float16)a[0]; h[1] = (_Float16)a[1];
    h[2] = (_Float16)a[2]; h[3] = (_Float16)a[3];
    h[4] = (_Float16)b[0]; h[5] = (_Float16)b[1];
    h[6] = (_Float16)b[2]; h[7] = (_Float16)b[3];
    return h;
}

// ---------------- Kernel A: qh = (x@Wq^T)*scale, kh = x@Wk^T (fp16 out) -------
__global__ void __launch_bounds__(256)
qk_proj(const float* __restrict__ x, const float* __restrict__ Wq,
        const float* __restrict__ Wk, _Float16* __restrict__ qh,
        _Float16* __restrict__ kh) {
    __shared__ __align__(16) _Float16 Wql[16][264];
    __shared__ __align__(16) _Float16 Wkl[16][264];
    const int tid = threadIdx.x;
    const int wave = tid >> 6, lane = tid & 63;
    const int g = lane >> 4, l16 = lane & 15;
    const int rowblk = blockIdx.x >> 1, thalf = blockIdx.x & 1;
    const size_t r0 = ((size_t)rowblk * 4 + wave) * 16;

    half8 xa[8];
#pragma unroll
    for (int c = 0; c < 8; ++c)
        xa[c] = cvt8(x + (r0 + l16) * DD + c * 32 + g * 8);

    for (int i = 0; i < 8; ++i) {
        const int t = thalf * 8 + i;
        __syncthreads();
        {
            const int sel = tid >> 7;
            const int tt  = tid & 127;
            const int row = tt >> 3;
            const int col = (tt & 7) * 32;
            const float* src = (sel ? Wk : Wq) + (size_t)(t * 16 + row) * DD + col;
            _Float16* dst = sel ? &Wkl[row][col] : &Wql[row][col];
#pragma unroll
            for (int j = 0; j < 4; ++j)
                *(half8*)(dst + j * 8) = cvt8(src + j * 8);
        }
        __syncthreads();
        f32x4 aq = {0.f, 0.f, 0.f, 0.f}, ak = {0.f, 0.f, 0.f, 0.f};
#pragma unroll
        for (int c = 0; c < 8; ++c) {
            half8 bq = *(const half8*)&Wql[l16][c * 32 + g * 8];
            half8 bk = *(const half8*)&Wkl[l16][c * 32 + g * 8];
            aq = __builtin_amdgcn_mfma_f32_16x16x32_f16(xa[c], bq, aq, 0, 0, 0);
            ak = __builtin_amdgcn_mfma_f32_16x16x32_f16(xa[c], bk, ak, 0, 0, 0);
        }
#pragma unroll
        for (int r = 0; r < 4; ++r) {
            size_t row = r0 + g * 4 + r;
            qh[row * DD + t * 16 + l16] = (_Float16)(aq[r] * 0.0625f);
            kh[row * DD + t * 16 + l16] = (_Float16)ak[r];
        }
    }
}

// ---------------- Kernel B: xT[b][d][n] = (fp16) x[b][n][d] ----------------
__global__ void __launch_bounds__(256)
x_transpose(const float* __restrict__ x, _Float16* __restrict__ xT) {
    __shared__ _Float16 tl[32][33];
    const int b = blockIdx.z;
    const int n0 = blockIdx.y * 32, d0 = blockIdx.x * 32;
    const int c = threadIdx.x & 31, rq = threadIdx.x >> 5;
#pragma unroll
    for (int i = 0; i < 4; ++i) {
        int row = rq + i * 8;
        tl[row][c] = (_Float16)x[((size_t)b * NN + n0 + row) * DD + d0 + c];
    }
    __syncthreads();
#pragma unroll
    for (int i = 0; i < 4; ++i) {
        int dr = rq + i * 8;
        xT[((size_t)b * DD + d0 + dr) * NN + n0 + c] = tl[c][dr];
    }
}

// ---------------- Kernel C: flash attention, 32q/wave + swapped QK^T ---------
// 4 waves x 32 q-rows = 128 q/block. KV-step 32. Swapped S^T = mfma(K, Q):
// lane owns 2 q-rows -> in-register softmax (in-lane max/sum + 2 shfl), P
// redistributed to PV A-frag layout via cvt_pkrtz + 16 shfl (Pl deleted).
// Each K/V fragment read feeds 2 MFMAs (halved LDS-pipe pressure vs R7).
// LDS 33KB; VGPR ~250 -> __launch_bounds__(256,2) = 2 waves/SIMD, 2 blk/CU.
__global__ void __launch_bounds__(256, 2)
attn(const _Float16* __restrict__ qh, const _Float16* __restrict__ kh,
     const _Float16* __restrict__ xT, float* __restrict__ out,
     _Float16* __restrict__ Op, float* __restrict__ ml, int lgS) {
    __shared__ __align__(16) _Float16 Kl[32][264];
    __shared__ __align__(16) _Float16 Vl[256 * 32];
    const int tid = threadIdx.x;
    const int wave = tid >> 6, lane = tid & 63;
    const int g = lane >> 4, l16 = lane & 15;
    const int S = 1 << lgS;
    const int b = blockIdx.x & 7;
    const int tt = blockIdx.x >> 3;
    const int s = tt & (S - 1);
    const int qb = tt >> lgS;
    const int wq0 = qb * 128 + wave * 32;
    const int kvlen = NN >> lgS;
    const int kv_begin = s * kvlen;

    const _Float16* qp = qh + ((size_t)b * NN + wq0) * DD;
    const _Float16* kb = kh + (size_t)b * NN * DD;
    const _Float16* vb = xT + (size_t)b * DD * NN;

    half8 qf[2][8];
#pragma unroll
    for (int t = 0; t < 2; ++t)
#pragma unroll
        for (int c = 0; c < 8; ++c)
            qf[t][c] = *(const half8*)(qp + (size_t)(t * 16 + l16) * DD + c * 32 + g * 8);

    f32x4 O[2][16];
    f32x4 zero = {0.f, 0.f, 0.f, 0.f};
#pragma unroll
    for (int t = 0; t < 2; ++t)
#pragma unroll
        for (int dt = 0; dt < 16; ++dt) O[t][dt] = zero;
    float m[2] = {-1e30f, -1e30f};
    float l[2] = {0.f, 0.f};

    for (int kv0 = kv_begin; kv0 < kv_begin + kvlen; kv0 += 32) {
        __syncthreads();
        {   // stage K tile: 32 rows x 256 d
            const int r = tid >> 3;
            const int ch = (tid & 7) * 8;
            const _Float16* src = kb + (size_t)(kv0 + r) * DD + ch;
#pragma unroll
            for (int j = 0; j < 4; ++j)
                *(half8*)&Kl[r][ch + j * 64] = *(const half8*)(src + j * 64);
        }
        {   // stage V tile: 256 d-rows x 32 kv
            const int vch = (tid & 3) * 8;
#pragma unroll
            for (int p = 0; p < 4; ++p) {
                int d = p * 64 + (tid >> 2);
                *(half8*)&Vl[d * 32 + vch] =
                    *(const half8*)(vb + (size_t)d * NN + kv0 + vch);
            }
        }
        __syncthreads();

        // swapped QK^T: S^T[kv][q], lane = q-col l16, rows kv = kt*16+g*4+r
        f32x4 s00 = zero, s01 = zero, s10 = zero, s11 = zero;
#pragma unroll
        for (int c = 0; c < 8; ++c) {
            half8 k0 = *(const half8*)&Kl[l16][c * 32 + g * 8];
            half8 k1 = *(const half8*)&Kl[16 + l16][c * 32 + g * 8];
            s00 = __builtin_amdgcn_mfma_f32_16x16x32_f16(k0, qf[0][c], s00, 0, 0, 0);
            s01 = __builtin_amdgcn_mfma_f32_16x16x32_f16(k1, qf[0][c], s01, 0, 0, 0);
            s10 = __builtin_amdgcn_mfma_f32_16x16x32_f16(k0, qf[1][c], s10, 0, 0, 0);
            s11 = __builtin_amdgcn_mfma_f32_16x16x32_f16(k1, qf[1][c], s11, 0, 0, 0);
        }

        // per-q-row (in-lane) max, then 2-shfl cross-g reduce
        float tm[2];
#pragma unroll
        for (int t = 0; t < 2; ++t) {
            const f32x4& a = t ? s10 : s00;
            const f32x4& c = t ? s11 : s01;
            float v = fmaxf(fmaxf(fmaxf(a[0], a[1]), fmaxf(a[2], a[3])),
                            fmaxf(fmaxf(c[0], c[1]), fmaxf(c[2], c[3])));
            v = fmaxf(v, __shfl_xor(v, 16));
            v = fmaxf(v, __shfl_xor(v, 32));
            tm[t] = v;
        }
        bool need = (tm[0] > m[0] + 8.f) || (tm[1] > m[1] + 8.f);
        if (__ballot(need)) {
#pragma unroll
            for (int t = 0; t < 2; ++t) {
                float nm = fmaxf(m[t], tm[t]);
                float al = __expf(m[t] - nm);
                m[t] = nm;
                l[t] *= al;
                float alr[4];
#pragma unroll
                for (int r = 0; r < 4; ++r) alr[r] = __shfl(al, g * 4 + r);
#pragma unroll
                for (int dt = 0; dt < 16; ++dt)
#pragma unroll
                    for (int r = 0; r < 4; ++r) O[t][dt][r] *= alr[r];
            }
        }

        // exp + row-sum + pack to fp16 pairs + shfl-redistribute to A-frag
        half8 pa[2];
#pragma unroll
        for (int t = 0; t < 2; ++t) {
            f32x4 e0, e1;
            const f32x4& a = t ? s10 : s00;
            const f32x4& c = t ? s11 : s01;
#pragma unroll
            for (int r = 0; r < 4; ++r) {
                e0[r] = __expf(a[r] - m[t]);
                e1[r] = __expf(c[r] - m[t]);
            }
            float rs = (e0[0] + e0[1]) + (e0[2] + e0[3]) +
                       (e1[0] + e1[1]) + (e1[2] + e1[3]);
            rs += __shfl_xor(rs, 16);
            rs += __shfl_xor(rs, 32);
            l[t] += rs;

            unsigned pk0[2], pk1[2];
            pk0[0] = __builtin_bit_cast(unsigned, __builtin_amdgcn_cvt_pkrtz(e0[0], e0[1]));
            pk0[1] = __builtin_bit_cast(unsigned, __builtin_amdgcn_cvt_pkrtz(e0[2], e0[3]));
            pk1[0] = __builtin_bit_cast(unsigned, __builtin_amdgcn_cvt_pkrtz(e1[0], e1[1]));
            pk1[1] = __builtin_bit_cast(unsigned, __builtin_amdgcn_cvt_pkrtz(e1[2], e1[3]));

            const int sl0 = l16 + ((lane & 16) ? 32 : 0);  // 32*(g&1)
            uint4v w;
#pragma unroll
            for (int j2 = 0; j2 < 4; ++j2) {
                int sl = sl0 + ((j2 >> 1) << 4);
                unsigned u0 = __shfl((int)pk0[j2 & 1], sl);
                unsigned u1 = __shfl((int)pk1[j2 & 1], sl);
                w[j2] = (g >= 2) ? u1 : u0;
            }
            pa[t] = __builtin_bit_cast(half8, w);
        }

        // PV: each V-frag feeds both q-tiles
#pragma unroll
        for (int dt = 0; dt < 16; ++dt) {
            half8 vf = *(const half8*)&Vl[(dt * 16 + l16) * 32 + g * 8];
            O[0][dt] = __builtin_amdgcn_mfma_f32_16x16x32_f16(pa[0], vf, O[0][dt], 0, 0, 0);
            O[1][dt] = __builtin_amdgcn_mfma_f32_16x16x32_f16(pa[1], vf, O[1][dt], 0, 0, 0);
        }
    }

    if (lgS == 0) {
#pragma unroll
        for (int t = 0; t < 2; ++t) {
            float rl = 1.0f / l[t];
            float rlr[4];
#pragma unroll
            for (int r = 0; r < 4; ++r) rlr[r] = __shfl(rl, g * 4 + r);
            float* ob = out + ((size_t)b * NN + wq0 + t * 16) * DD;
#pragma unroll
            for (int dt = 0; dt < 16; ++dt)
#pragma unroll
                for (int r = 0; r < 4; ++r)
                    ob[(size_t)(g * 4 + r) * DD + dt * 16 + l16] = O[t][dt][r] * rlr[r];
        }
    } else {
#pragma unroll
        for (int t = 0; t < 2; ++t) {
            float rl = 1.0f / l[t];
            float rlr[4];
#pragma unroll
            for (int r = 0; r < 4; ++r) rlr[r] = __shfl(rl, g * 4 + r);
            _Float16* ow = Op + (((size_t)s * BB + b) * NN + wq0 + t * 16) * DD;
#pragma unroll
            for (int dt = 0; dt < 16; ++dt)
#pragma unroll
                for (int r = 0; r < 4; ++r)
                    ow[(dt * 4 + r) * 64 + lane] = (_Float16)(O[t][dt][r] * rlr[r]);
        }
        if (lane < 16) {
            float* mlp = ml + (((size_t)s * BB + b) * NN + wq0) * 2;
#pragma unroll
            for (int t = 0; t < 2; ++t) {
                mlp[(t * 16 + lane) * 2]     = m[t];
                mlp[(t * 16 + lane) * 2 + 1] = l[t];
            }
        }
    }
}

// ---------------- Kernel D: combine permuted fp16 partials ----------------
__global__ void __launch_bounds__(256)
combine(const _Float16* __restrict__ Op, const float* __restrict__ ml,
        float* __restrict__ out, int S) {
    const int row = blockIdx.x * 4 + (threadIdx.x >> 6);
    const int c0  = (threadIdx.x & 63) * 4;
    const int widx = ((c0 >> 4) * 4 + (row & 3)) * 64 + ((row >> 2) & 3) * 16 + (c0 & 15);
    const size_t rbase = (size_t)(row & ~15) * DD + widx;

    float M = -1e30f;
    for (int s = 0; s < S; ++s)
        M = fmaxf(M, ml[((size_t)s * BB * NN + row) * 2]);
    float wsum = 0.f;
    f32x4 acc = {0.f, 0.f, 0.f, 0.f};
    for (int s = 0; s < S; ++s) {
        const float* mlp = ml + ((size_t)s * BB * NN + row) * 2;
        float w = __expf(mlp[0] - M) * mlp[1];
        wsum += w;
        half4 o = *(const half4*)(Op + (size_t)s * BB * NN * DD + rbase);
        acc[0] += w * (float)o[0]; acc[1] += w * (float)o[1];
        acc[2] += w * (float)o[2]; acc[3] += w * (float)o[3];
    }
    float inv = 1.0f / wsum;
    f32x4 res = {acc[0] * inv, acc[1] * inv, acc[2] * inv, acc[3] * inv};
    *(f32x4*)(out + (size_t)row * DD + c0) = res;
}

extern "C" void kernel_launch(void* const* d_in, const int* in_sizes, int n_in,
                              void* d_out, int out_size, void* d_ws, size_t ws_size,
                              hipStream_t stream) {
    const float* x  = (const float*)d_in[0];
    const float* Wq = (const float*)d_in[1];
    const float* Wk = (const float*)d_in[2];
    float* out = (float*)d_out;

    const size_t NTOK = (size_t)BB * NN;
    const size_t HBUF = NTOK * DD * sizeof(_Float16);
    _Float16* qh = (_Float16*)d_ws;
    _Float16* kh = qh + NTOK * DD;
    _Float16* xT = kh + NTOK * DD;
    const size_t base = 3 * HBUF;
    const size_t OSZ  = NTOK * DD * sizeof(_Float16);
    const size_t MLSZ = NTOK * 2 * sizeof(float);

    int lgS = 0;
    if (ws_size >= base + 4 * (OSZ + MLSZ)) lgS = 2;
    else if (ws_size >= base + 2 * (OSZ + MLSZ)) lgS = 1;
    const int S = 1 << lgS;

    _Float16* Op = (_Float16*)((char*)d_ws + base);
    float* ml = (float*)((char*)d_ws + base + (size_t)S * OSZ);

    qk_proj<<<dim3(BB * NN / 64 * 2), dim3(256), 0, stream>>>(x, Wq, Wk, qh, kh);
    x_transpose<<<dim3(DD / 32, NN / 32, BB), dim3(256), 0, stream>>>(x, xT);
    attn<<<dim3(BB * (NN / 128) * S), dim3(256), 0, stream>>>(qh, kh, xT, out, Op, ml, lgS);
    if (S > 1)
        combine<<<dim3(BB * NN / 4), dim3(256), 0, stream>>>(Op, ml, out, S);
}